// Round 13
// baseline (6554.897 us; speedup 1.0000x reference)
//
#include <hip/hip_runtime.h>
#include <math.h>

#define NP    7056
#define NP2   7168   // padded row count
#define NPS   84
#define CCH   4
#define HW    49
#define HWR   784
#define KF    196    // CCH*HW
#define KSEG  196    // one split segment
#define KC    608    // 3*196 = 588, padded to 19 half-K steps of 32
#define NH    19     // half-K steps of 32
#define NA    10
#define SLR   256
#define GK    17

typedef _Float16 half8 __attribute__((ext_vector_type(8)));
typedef float f32x4 __attribute__((ext_vector_type(4)));

// ---------------- separable gaussian blur (only at subsampled points) ----------------
__global__ void hpass_kernel(const float* __restrict__ hr, float* __restrict__ htmp) {
    __shared__ float g[GK];
    int tid = threadIdx.x;
    if (tid < GK) {
        double s = 0.0, mine = 0.0;
        for (int k = 0; k < GK; k++) {
            double ax = (double)k - 8.0;
            double e = exp(-ax * ax / 32.0);
            s += e;
            if (k == tid) mine = e;
        }
        g[tid] = (float)(mine / s);
    }
    __syncthreads();
    int gid = blockIdx.x * 256 + tid;      // 4*1024*256 exact
    int xs = gid & 255;
    int y  = (gid >> 8) & 1023;
    int c  = gid >> 18;
    const float* row = hr + (size_t)(c * 1024 + y) * 1024;
    int xb = xs * 4 - 6;
    float acc = 0.f;
#pragma unroll
    for (int k = 0; k < GK; k++) {
        int xc = xb + k;
        float v = (xc >= 0 && xc < 1024) ? row[xc] : 0.f;
        acc = fmaf(g[k], v, acc);
    }
    htmp[gid] = acc;
}

__global__ void vpass_kernel(const float* __restrict__ htmp, const float* __restrict__ ms,
                             float* __restrict__ diff) {
    __shared__ float g[GK];
    int tid = threadIdx.x;
    if (tid < GK) {
        double s = 0.0, mine = 0.0;
        for (int k = 0; k < GK; k++) {
            double ax = (double)k - 8.0;
            double e = exp(-ax * ax / 32.0);
            s += e;
            if (k == tid) mine = e;
        }
        g[tid] = (float)(mine / s);
    }
    __syncthreads();
    int gid = blockIdx.x * 256 + tid;      // 4*256*256 exact
    int xs = gid & 255;
    int ys = (gid >> 8) & 255;
    int c  = gid >> 16;
    int yb = ys * 4 - 6;
    float acc = 0.f;
#pragma unroll
    for (int k = 0; k < GK; k++) {
        int yc = yb + k;
        float v = (yc >= 0 && yc < 1024) ? htmp[(size_t)(c * 1024 + yc) * 256 + xs] : 0.f;
        acc = fmaf(g[k], v, acc);
    }
    diff[gid] = ms[gid] - acc;
}

// ---------------- unfold residual patches: y[b=n*4+c][p] ----------------
__global__ void build_y_kernel(const float* __restrict__ diff, float* __restrict__ yb) {
    int gid = blockIdx.x * 256 + threadIdx.x;
    if (gid >= NP * CCH * HW) return;
    int p = gid % HW;
    int b = gid / HW;
    int c = b & 3;
    int n = b >> 2;
    int py = n / NPS, px = n % NPS;
    int dy = p / 7, dx = p % 7;
    yb[gid] = diff[(size_t)(c * SLR + py * 3 + dy) * SLR + px * 3 + dx];
}

// ---------------- dict -> concatenated split [Dh | Dl | Dh | 0pad], K=608, half8 -------
__global__ void splitcat_kernel(const float* __restrict__ src, _Float16* __restrict__ Dcat) {
    int gid = blockIdx.x * 256 + threadIdx.x;   // NP2*76 exact
    int r = gid / 76, v8 = gid - r * 76;
    const float* srow = src + (size_t)r * KF;
    bool valid = (r < NP);
    half8 o;
#pragma unroll
    for (int e = 0; e < 8; e++) {
        int k = v8 * 8 + e;
        int seg = (k >= 392) ? 2 : (k >= 196 ? 1 : 0);
        int ks = k - seg * 196;
        float x = (valid && k < 588) ? srow[ks] : 0.f;
        _Float16 hi = (_Float16)x;
        o[e] = (seg == 1) ? (_Float16)(x - (float)hi) : hi;
    }
    *(half8*)&Dcat[(size_t)r * KC + v8 * 8] = o;
}

// ---------------- fp32 hr_dict -> fp16 (vectorized) ----------------
__global__ void hd16_kernel(const float* __restrict__ hr_dict, _Float16* __restrict__ hd) {
    int gid = blockIdx.x * 256 + threadIdx.x;
    if (gid >= (NP * CCH * HWR) / 8) return;
    const float4 a = *(const float4*)&hr_dict[(size_t)gid * 8];
    const float4 b = *(const float4*)&hr_dict[(size_t)gid * 8 + 4];
    half8 o;
    o[0] = (_Float16)a.x; o[1] = (_Float16)a.y; o[2] = (_Float16)a.z; o[3] = (_Float16)a.w;
    o[4] = (_Float16)b.x; o[5] = (_Float16)b.y; o[6] = (_Float16)b.z; o[7] = (_Float16)b.w;
    *(half8*)&hd[(size_t)gid * 8] = o;
}

// -------- 256x128x608 MFMA GEMM + row argmax, 2-buf / 3-blocks-per-CU pipeline --------
__device__ __forceinline__ unsigned long long shfl_xor_u64(unsigned long long v, int m) {
    unsigned int lo = (unsigned int)v;
    unsigned int hi = (unsigned int)(v >> 32);
    lo = __shfl_xor(lo, m, 64);
    hi = __shfl_xor(hi, m, 64);
    return ((unsigned long long)hi << 32) | (unsigned long long)lo;
}

__device__ __forceinline__ void gload16(const void* g, void* l) {
    __builtin_amdgcn_global_load_lds((const __attribute__((address_space(1))) void*)(void*)g,
                                     (__attribute__((address_space(3))) void*)l, 16, 0, 0);
}

// LDS (halves): buf q in {0,1} at q*12288: A half [256 rows][32 k] at 0,
// B half [128 rows][32 k] at 8192. Slot XOR applied on pre-swizzled GLOBAL
// source (LDS dest linear) and on reads. 48 KB -> 3 blocks/CU (24 waves/CU).
__global__ __launch_bounds__(512, 6) void mfma_argmax_kernel(
    const _Float16* __restrict__ Rcat, const _Float16* __restrict__ Dcat,
    unsigned long long* __restrict__ keys, int seg) {
    __shared__ __align__(16) _Float16 lds[2 * 12288];
    const int tid = threadIdx.x;
    const int lane = tid & 63;
    const int wave = tid >> 6;            // 0..7
    const int wm = wave >> 1;             // 0..3: A 64-row block
    const int wn = wave & 1;              // 0..1: B 64-col block

    // XCD chunking (r6/r9 empirical best): 1568 blocks = 8 XCD x (28 by x 7 bx), by FAST.
    int b0 = (int)blockIdx.x;
    int xcd = b0 & 7, w = b0 >> 3;
    int by = w % 28;
    int bx = xcd * 7 + w / 28;
    const int row0 = by * 256, col0 = bx * 128;

    const int lr = lane & 15, lk = lane >> 4;
    const int xk = (lk ^ ((lr >> 1) & 3)) * 8;
    const int aBase = (wm * 64 + lr) * 32 + xk;          // + u*512
    const int bBase = 8192 + (wn * 64 + lr) * 32 + xk;   // + v*512

    // staging: wave w stages A rows w*16..w*16+15 (+128), B rows w*16..w*16+15
    const int srow = wave * 16 + (lane >> 2);
    const int sc = ((lane & 3) ^ ((lane >> 3) & 3)) * 8;   // pre-swizzled source chunk
    const _Float16* pA = Rcat + (size_t)(row0 + srow) * KC + sc;
    const _Float16* pB = Dcat + (size_t)(col0 + srow) * KC + sc;
    const int dA1 = wave * 512, dA2 = 4096 + wave * 512, dB = 8192 + wave * 512;

    // hsrc = which K-half's bytes to load (clamped for tail dup);
    // dstp = destination buffer (always (h+1)&1 in the loop -> never the live buf).
    auto STAGE = [&](int hsrc, int dstp) {
        int q = dstp * 12288;
        int off = hsrc * 32;
        gload16(pA + off, &lds[q + dA1]);
        gload16(pA + (size_t)128 * KC + off, &lds[q + dA2]);
        gload16(pB + off, &lds[q + dB]);
    };

    f32x4 acc[4][4];
#pragma unroll
    for (int u = 0; u < 4; u++)
#pragma unroll
        for (int v = 0; v < 4; v++) {
            f32x4 zz = {0.f, 0.f, 0.f, 0.f};
            acc[u][v] = zz;
        }

    // prologue: half 0 into buf 0 (3 loads outstanding)
    STAGE(0, 0);

    for (int h = 0; h < NH; ++h) {
        const int q = (h & 1) * 12288;
        int hn = h + 1; if (hn > NH - 1) hn = NH - 1;   // clamped source (tail dup)
        STAGE(hn, (h + 1) & 1);
        // outstanding <= 6 (STAGE(h) + STAGE(h+1)); wait 3 -> STAGE(h) landed
        asm volatile("s_waitcnt vmcnt(3)" ::: "memory");
        __builtin_amdgcn_s_barrier();

        half8 aF[4], bF[4];
#pragma unroll
        for (int u = 0; u < 4; ++u)
            aF[u] = *(const half8*)&lds[q + aBase + u * 512];
#pragma unroll
        for (int v = 0; v < 4; ++v)
            bF[v] = *(const half8*)&lds[q + bBase + v * 512];

        __builtin_amdgcn_s_setprio(1);
#pragma unroll
        for (int u = 0; u < 4; ++u)
#pragma unroll
            for (int v = 0; v < 4; ++v)
                acc[u][v] = __builtin_amdgcn_mfma_f32_16x16x32_f16(aF[u], bF[v], acc[u][v], 0, 0, 0);
        __builtin_amdgcn_s_setprio(0);

        asm volatile("s_waitcnt lgkmcnt(0)" ::: "memory");   // all reads of buf q retired
        __builtin_amdgcn_s_barrier();
    }
    asm volatile("s_waitcnt vmcnt(0)" ::: "memory");

    // argmax epilogue: C/D layout col=lane&15, row=(lane>>4)*4+j
    unsigned long long* kseg = keys + (size_t)seg * NP;
#pragma unroll
    for (int u = 0; u < 4; u++)
#pragma unroll
        for (int j = 0; j < 4; j++) {
            unsigned long long key = 0ull;
#pragma unroll
            for (int v = 0; v < 4; v++) {
                int gc = col0 + wn * 64 + v * 16 + lr;
                if (gc < NP) {
                    unsigned int bits = __float_as_uint(fabsf(acc[u][v][j]));
                    unsigned long long k2 = ((unsigned long long)bits << 32) |
                                            (unsigned long long)(0xFFFFFFFFu - (unsigned int)gc);
                    key = (k2 > key) ? k2 : key;
                }
            }
#pragma unroll
            for (int m = 1; m < 16; m <<= 1) {
                unsigned long long o = shfl_xor_u64(key, m);
                key = (o > key) ? o : key;
            }
            if (lr == 0) {
                int gr = row0 + wm * 64 + u * 16 + lk * 4 + j;
                if (gr < NP) atomicMax(kseg + gr, key);
            }
        }
}

// ------- wave-parallel least squares + FUSED residual split: one wave per patch -------
template <int M>
__global__ __launch_bounds__(256) void solve_kernel(
    const float* __restrict__ yb, const float* __restrict__ dict,
    const unsigned long long* __restrict__ keys9,
    int* __restrict__ idxb, float* __restrict__ alphab,
    _Float16* __restrict__ Rcat) {
    int n = (blockIdx.x * 256 + threadIdx.x) >> 6;   // grid = NP/4 blocks exact
    int lane = threadIdx.x & 63;
    int g = lane >> 4, t = lane & 15;                // channel group, lane-in-group

    int newidx = 0;
    if (M >= 2) newidx = (int)(0xFFFFFFFFu -
        (unsigned int)(keys9[(size_t)(M - 2) * NP + n] & 0xFFFFFFFFull));
    if (lane == 0) {
        if (M == 1) idxb[n * NA] = n;                // index[:,0] = arange
        else        idxb[n * NA + (M - 1)] = newidx;
    }

    int id[M];
#pragma unroll
    for (int k = 0; k < M; k++)
        id[k] = (k == 0) ? n : ((M >= 2 && k == M - 1) ? newidx : idxb[n * NA + k]);

    const int b = n * CCH + g;
    const int base_c = g * HW;

    constexpr int TRI = M * (M + 1) / 2;
    float G[TRI];
    float rhs[M];
#pragma unroll
    for (int q = 0; q < TRI; q++) G[q] = 0.f;
#pragma unroll
    for (int k = 0; k < M; k++) rhs[k] = 0.f;

    // lanes split the 49 pixels: p = t, t+16, t+32 (+48 on t==0)
#pragma unroll
    for (int rep = 0; rep < 4; rep++) {
        int p = t + rep * 16;
        if (p < HW) {
            float a[M];
#pragma unroll
            for (int k = 0; k < M; k++)
                a[k] = dict[(size_t)id[k] * KF + base_c + p];
            float yp = yb[(size_t)b * HW + p];
#pragma unroll
            for (int k = 0; k < M; k++) {
                rhs[k] = fmaf(a[k], yp, rhs[k]);
#pragma unroll
                for (int l = 0; l <= k; l++)
                    G[k * (k + 1) / 2 + l] = fmaf(a[k], a[l], G[k * (k + 1) / 2 + l]);
            }
        }
    }

    // tree-reduce across the 16-lane group (xor masks 1..8 stay in-group)
#pragma unroll
    for (int m = 1; m < 16; m <<= 1) {
#pragma unroll
        for (int q = 0; q < TRI; q++) G[q] += __shfl_xor(G[q], m, 64);
#pragma unroll
        for (int k = 0; k < M; k++) rhs[k] += __shfl_xor(rhs[k], m, 64);
    }

    // Cholesky in place (redundant on all lanes; store inverse diagonal)
#pragma unroll
    for (int k = 0; k < M; k++) {
        float s = G[k * (k + 1) / 2 + k];
#pragma unroll
        for (int j = 0; j < k; j++) {
            float l = G[k * (k + 1) / 2 + j];
            s = fmaf(-l, l, s);
        }
        float inv = 1.0f / sqrtf(fmaxf(s, 1e-30f));
        G[k * (k + 1) / 2 + k] = inv;
#pragma unroll
        for (int r = k + 1; r < M; r++) {
            float tt = G[r * (r + 1) / 2 + k];
#pragma unroll
            for (int j = 0; j < k; j++)
                tt = fmaf(-G[r * (r + 1) / 2 + j], G[k * (k + 1) / 2 + j], tt);
            G[r * (r + 1) / 2 + k] = tt * inv;
        }
    }
    // forward: L z = rhs
#pragma unroll
    for (int k = 0; k < M; k++) {
        float tt = rhs[k];
#pragma unroll
        for (int j = 0; j < k; j++) tt = fmaf(-G[k * (k + 1) / 2 + j], rhs[j], tt);
        rhs[k] = tt * G[k * (k + 1) / 2 + k];
    }
    // backward: L^T alpha = z
#pragma unroll
    for (int k = M - 1; k >= 0; k--) {
        float tt = rhs[k];
#pragma unroll
        for (int j = k + 1; j < M; j++) tt = fmaf(-G[j * (j + 1) / 2 + k], rhs[j], tt);
        rhs[k] = tt * G[k * (k + 1) / 2 + k];
    }

    if (t == 0) {
#pragma unroll
        for (int k = 0; k < M; k++) alphab[(size_t)b * NA + k] = rhs[k];
    }

    // FUSED residual -> fp16 hi/hi/lo segments (same pixels this lane already owns)
    if (M < NA) {
        _Float16* r0 = Rcat + (size_t)n * KC + base_c;
#pragma unroll
        for (int rep = 0; rep < 4; rep++) {
            int p = t + rep * 16;
            if (p < HW) {
                float s = yb[(size_t)b * HW + p];
#pragma unroll
                for (int k = 0; k < M; k++)
                    s = fmaf(-rhs[k], dict[(size_t)id[k] * KF + base_c + p], s);
                _Float16 hi = (_Float16)s;
                r0[p] = hi;
                r0[KSEG + p] = hi;
                r0[2 * KSEG + p] = (_Float16)(s - (float)hi);
            }
        }
    }
}

// ---------------- stage A: per-patch HR reconstruction (fp16, half8 gathers) ----------
__global__ __launch_bounds__(256) void recon_kernel(
    const float* __restrict__ alphab, const int* __restrict__ idxb,
    const _Float16* __restrict__ hd, _Float16* __restrict__ hr_p) {
    int n = blockIdx.x;
    int tid = threadIdx.x;
    __shared__ float al[CCH * NA];
    __shared__ int idn[NA];
    if (tid < CCH * NA) al[tid] = alphab[(size_t)n * CCH * NA + tid];
    if (tid < NA) idn[tid] = idxb[n * NA + tid];
    __syncthreads();
    for (int v = tid; v < (CCH * HWR) / 8; v += 256) {   // 392 vecs of 8
        int c = v / (HWR / 8);                            // 98 vecs/channel
        float s[8] = {0.f, 0.f, 0.f, 0.f, 0.f, 0.f, 0.f, 0.f};
#pragma unroll
        for (int k = 0; k < NA; k++) {
            half8 d = *(const half8*)&hd[(size_t)idn[k] * (CCH * HWR) + v * 8];
            float ak = al[c * NA + k];
#pragma unroll
            for (int e = 0; e < 8; e++) s[e] = fmaf(ak, (float)d[e], s[e]);
        }
        half8 o;
#pragma unroll
        for (int e = 0; e < 8; e++) o[e] = (_Float16)s[e];
        *(half8*)&hr_p[(size_t)n * (CCH * HWR) + v * 8] = o;
    }
}

// ---------------- stage B: streaming fold + finalize ----------------
__global__ __launch_bounds__(256) void fold2_kernel(
    const _Float16* __restrict__ hr_p, const float* __restrict__ divisor,
    const float* __restrict__ hrms, const float* __restrict__ lms,
    float* __restrict__ out) {
    int gid = blockIdx.x * 256 + threadIdx.x;  // 4*1024*1024 exact
    int x  = gid & 1023;
    int yy = (gid >> 10) & 1023;
    int c  = gid >> 20;

    int t0 = yy - 27;
    int py0 = (t0 > 0) ? (t0 + 11) / 12 : 0;
    int py1 = min(83, yy / 12);
    int s0 = x - 27;
    int px0 = (s0 > 0) ? (s0 + 11) / 12 : 0;
    int px1 = min(83, x / 12);

    float acc = 0.f;
    for (int py = py0; py <= py1; py++) {
        int qy = yy - py * 12;
        for (int px = px0; px <= px1; px++) {
            int qx = x - px * 12;
            int n = py * NPS + px;
            acc += (float)hr_p[(size_t)n * (CCH * HWR) + c * HWR + qy * 28 + qx];
        }
    }
    out[gid] = acc / (divisor[gid] + 1e-8f) + hrms[gid] + lms[gid];
}

// ---------------- fallback one-stage fold (if ws too small for hd16/hr_p) -------------
__global__ __launch_bounds__(256) void fold_final_kernel(
    const float* __restrict__ alphab, const int* __restrict__ idxb,
    const float* __restrict__ hr_dict, const float* __restrict__ divisor,
    const float* __restrict__ hrms, const float* __restrict__ lms,
    float* __restrict__ out) {
    int gid = blockIdx.x * 256 + threadIdx.x;
    int x  = gid & 1023;
    int yy = (gid >> 10) & 1023;
    int c  = gid >> 20;
    int t0 = yy - 27;
    int py0 = (t0 > 0) ? (t0 + 11) / 12 : 0;
    int py1 = min(83, yy / 12);
    int s0 = x - 27;
    int px0 = (s0 > 0) ? (s0 + 11) / 12 : 0;
    int px1 = min(83, x / 12);
    float acc = 0.f;
    for (int py = py0; py <= py1; py++) {
        int qy = yy - py * 12;
        for (int px = px0; px <= px1; px++) {
            int qx = x - px * 12;
            int n = py * NPS + px;
            const float* al = alphab + (size_t)(n * CCH + c) * NA;
            const int* idn = idxb + n * NA;
            int q = qy * 28 + qx;
            float s = 0.f;
#pragma unroll
            for (int k = 0; k < NA; k++)
                s = fmaf(al[k], hr_dict[(size_t)idn[k] * (CCH * HWR) + c * HWR + q], s);
            acc += s;
        }
    }
    out[gid] = acc / (divisor[gid] + 1e-8f) + hrms[gid] + lms[gid];
}

// ---------------- launch ----------------
extern "C" void kernel_launch(void* const* d_in, const int* in_sizes, int n_in,
                              void* d_out, int out_size, void* d_ws, size_t ws_size,
                              hipStream_t stream) {
    const float* hrms    = (const float*)d_in[0];
    const float* ms      = (const float*)d_in[1];
    const float* lms     = (const float*)d_in[2];
    const float* lr_dict = (const float*)d_in[3];
    const float* hr_dict = (const float*)d_in[4];
    const float* divisor = (const float*)d_in[5];
    float* out = (float*)d_out;

    char* ws = (char*)d_ws;
    size_t off = 0;
    auto alloc = [&](size_t bytes) -> void* {
        void* p = ws + off;
        off += (bytes + 255) & ~(size_t)255;
        return p;
    };
    float* htmp   = (float*)alloc((size_t)4 * 1024 * 256 * 4);
    float* diff   = (float*)alloc((size_t)4 * 256 * 256 * 4);
    float* yb     = (float*)alloc((size_t)NP * CCH * HW * 4);
    float* alphab = (float*)alloc((size_t)NP * CCH * NA * 4);
    int*   idxb   = (int*)alloc((size_t)NP * NA * 4);
    unsigned long long* keys9 = (unsigned long long*)alloc((size_t)NP * 9 * 8);
    _Float16* Dcat = (_Float16*)alloc((size_t)NP2 * KC * 2);
    _Float16* Rcat = (_Float16*)alloc((size_t)NP2 * KC * 2);
    _Float16* hd16 = (_Float16*)alloc((size_t)NP * CCH * HWR * 2);
    _Float16* hr_p = (_Float16*)alloc((size_t)NP * CCH * HWR * 2);
    bool two_stage = (off <= ws_size);

    hpass_kernel<<<4096, 256, 0, stream>>>(hrms, htmp);
    vpass_kernel<<<1024, 256, 0, stream>>>(htmp, ms, diff);
    build_y_kernel<<<(NP * CCH * HW + 255) / 256, 256, 0, stream>>>(diff, yb);
    splitcat_kernel<<<(NP2 * 76) / 256, 256, 0, stream>>>(lr_dict, Dcat);
    hipMemsetAsync(keys9, 0, (size_t)NP * 9 * 8, stream);
    if (two_stage)
        hd16_kernel<<<((NP * CCH * HWR) / 8 + 255) / 256, 256, 0, stream>>>(hr_dict, hd16);

    int sblocks = NP / 4;                       // 1764: one wave per patch
    for (int i = 0; i < NA; i++) {
        if (i > 0)
            mfma_argmax_kernel<<<1568, 512, 0, stream>>>(Rcat, Dcat, keys9, i - 1);
        switch (i + 1) {
            case 1:  solve_kernel<1><<<sblocks, 256, 0, stream>>>(yb, lr_dict, keys9, idxb, alphab, Rcat); break;
            case 2:  solve_kernel<2><<<sblocks, 256, 0, stream>>>(yb, lr_dict, keys9, idxb, alphab, Rcat); break;
            case 3:  solve_kernel<3><<<sblocks, 256, 0, stream>>>(yb, lr_dict, keys9, idxb, alphab, Rcat); break;
            case 4:  solve_kernel<4><<<sblocks, 256, 0, stream>>>(yb, lr_dict, keys9, idxb, alphab, Rcat); break;
            case 5:  solve_kernel<5><<<sblocks, 256, 0, stream>>>(yb, lr_dict, keys9, idxb, alphab, Rcat); break;
            case 6:  solve_kernel<6><<<sblocks, 256, 0, stream>>>(yb, lr_dict, keys9, idxb, alphab, Rcat); break;
            case 7:  solve_kernel<7><<<sblocks, 256, 0, stream>>>(yb, lr_dict, keys9, idxb, alphab, Rcat); break;
            case 8:  solve_kernel<8><<<sblocks, 256, 0, stream>>>(yb, lr_dict, keys9, idxb, alphab, Rcat); break;
            case 9:  solve_kernel<9><<<sblocks, 256, 0, stream>>>(yb, lr_dict, keys9, idxb, alphab, Rcat); break;
            case 10: solve_kernel<10><<<sblocks, 256, 0, stream>>>(yb, lr_dict, keys9, idxb, alphab, Rcat); break;
        }
    }

    if (two_stage) {
        recon_kernel<<<NP, 256, 0, stream>>>(alphab, idxb, hd16, hr_p);
        fold2_kernel<<<(4 * 1024 * 1024) / 256, 256, 0, stream>>>(hr_p, divisor, hrms, lms, out);
    } else {
        fold_final_kernel<<<(4 * 1024 * 1024) / 256, 256, 0, stream>>>(
            alphab, idxb, hr_dict, divisor, hrms, lms, out);
    }
}

// Round 14
// 1115.672 us; speedup vs baseline: 5.8753x; 5.8753x over previous
//
#include <hip/hip_runtime.h>
#include <math.h>

#define NP    7056
#define NP2   7168   // padded row count
#define NPS   84
#define CCH   4
#define HW    49
#define HWR   784
#define KF    196    // CCH*HW
#define KSEG  196    // one split segment
#define KC    608    // 3*196 = 588, padded to 19 half-K steps of 32
#define NH    19     // half-K steps of 32
#define NA    10
#define SLR   256
#define GK    17

typedef _Float16 half8 __attribute__((ext_vector_type(8)));
typedef float f32x4 __attribute__((ext_vector_type(4)));

// ---------------- separable gaussian blur (only at subsampled points) ----------------
__global__ void hpass_kernel(const float* __restrict__ hr, float* __restrict__ htmp) {
    __shared__ float g[GK];
    int tid = threadIdx.x;
    if (tid < GK) {
        double s = 0.0, mine = 0.0;
        for (int k = 0; k < GK; k++) {
            double ax = (double)k - 8.0;
            double e = exp(-ax * ax / 32.0);
            s += e;
            if (k == tid) mine = e;
        }
        g[tid] = (float)(mine / s);
    }
    __syncthreads();
    int gid = blockIdx.x * 256 + tid;      // 4*1024*256 exact
    int xs = gid & 255;
    int y  = (gid >> 8) & 1023;
    int c  = gid >> 18;
    const float* row = hr + (size_t)(c * 1024 + y) * 1024;
    int xb = xs * 4 - 6;
    float acc = 0.f;
#pragma unroll
    for (int k = 0; k < GK; k++) {
        int xc = xb + k;
        float v = (xc >= 0 && xc < 1024) ? row[xc] : 0.f;
        acc = fmaf(g[k], v, acc);
    }
    htmp[gid] = acc;
}

__global__ void vpass_kernel(const float* __restrict__ htmp, const float* __restrict__ ms,
                             float* __restrict__ diff) {
    __shared__ float g[GK];
    int tid = threadIdx.x;
    if (tid < GK) {
        double s = 0.0, mine = 0.0;
        for (int k = 0; k < GK; k++) {
            double ax = (double)k - 8.0;
            double e = exp(-ax * ax / 32.0);
            s += e;
            if (k == tid) mine = e;
        }
        g[tid] = (float)(mine / s);
    }
    __syncthreads();
    int gid = blockIdx.x * 256 + tid;      // 4*256*256 exact
    int xs = gid & 255;
    int ys = (gid >> 8) & 255;
    int c  = gid >> 16;
    int yb = ys * 4 - 6;
    float acc = 0.f;
#pragma unroll
    for (int k = 0; k < GK; k++) {
        int yc = yb + k;
        float v = (yc >= 0 && yc < 1024) ? htmp[(size_t)(c * 1024 + yc) * 256 + xs] : 0.f;
        acc = fmaf(g[k], v, acc);
    }
    diff[gid] = ms[gid] - acc;
}

// ---------------- unfold residual patches: y[b=n*4+c][p] ----------------
__global__ void build_y_kernel(const float* __restrict__ diff, float* __restrict__ yb) {
    int gid = blockIdx.x * 256 + threadIdx.x;
    if (gid >= NP * CCH * HW) return;
    int p = gid % HW;
    int b = gid / HW;
    int c = b & 3;
    int n = b >> 2;
    int py = n / NPS, px = n % NPS;
    int dy = p / 7, dx = p % 7;
    yb[gid] = diff[(size_t)(c * SLR + py * 3 + dy) * SLR + px * 3 + dx];
}

// ---------------- dict -> concatenated split [Dh | Dl | Dh | 0pad], K=608, half8 -------
__global__ void splitcat_kernel(const float* __restrict__ src, _Float16* __restrict__ Dcat) {
    int gid = blockIdx.x * 256 + threadIdx.x;   // NP2*76 exact
    int r = gid / 76, v8 = gid - r * 76;
    const float* srow = src + (size_t)r * KF;
    bool valid = (r < NP);
    half8 o;
#pragma unroll
    for (int e = 0; e < 8; e++) {
        int k = v8 * 8 + e;
        int seg = (k >= 392) ? 2 : (k >= 196 ? 1 : 0);
        int ks = k - seg * 196;
        float x = (valid && k < 588) ? srow[ks] : 0.f;
        _Float16 hi = (_Float16)x;
        o[e] = (seg == 1) ? (_Float16)(x - (float)hi) : hi;
    }
    *(half8*)&Dcat[(size_t)r * KC + v8 * 8] = o;
}

// ---------------- fp32 hr_dict -> fp16 (vectorized) ----------------
__global__ void hd16_kernel(const float* __restrict__ hr_dict, _Float16* __restrict__ hd) {
    int gid = blockIdx.x * 256 + threadIdx.x;
    if (gid >= (NP * CCH * HWR) / 8) return;
    const float4 a = *(const float4*)&hr_dict[(size_t)gid * 8];
    const float4 b = *(const float4*)&hr_dict[(size_t)gid * 8 + 4];
    half8 o;
    o[0] = (_Float16)a.x; o[1] = (_Float16)a.y; o[2] = (_Float16)a.z; o[3] = (_Float16)a.w;
    o[4] = (_Float16)b.x; o[5] = (_Float16)b.y; o[6] = (_Float16)b.z; o[7] = (_Float16)b.w;
    *(half8*)&hd[(size_t)gid * 8] = o;
}

// ---------------- 256x128x608 MFMA GEMM + row argmax, 3-buf deep pipeline (r12) --------
__device__ __forceinline__ unsigned long long shfl_xor_u64(unsigned long long v, int m) {
    unsigned int lo = (unsigned int)v;
    unsigned int hi = (unsigned int)(v >> 32);
    lo = __shfl_xor(lo, m, 64);
    hi = __shfl_xor(hi, m, 64);
    return ((unsigned long long)hi << 32) | (unsigned long long)lo;
}

__device__ __forceinline__ void gload16(const void* g, void* l) {
    __builtin_amdgcn_global_load_lds((const __attribute__((address_space(1))) void*)(void*)g,
                                     (__attribute__((address_space(3))) void*)l, 16, 0, 0);
}

// LDS (halves): buf q in {0,1,2} at q*12288: A half [256 rows][32 k] at 0,
// B half [128 rows][32 k] at 8192. Slot XOR applied on pre-swizzled GLOBAL
// source (LDS dest linear) and on reads.
__global__ __launch_bounds__(512, 4) void mfma_argmax_kernel(
    const _Float16* __restrict__ Rcat, const _Float16* __restrict__ Dcat,
    unsigned long long* __restrict__ keys, int seg) {
    __shared__ __align__(16) _Float16 lds[3 * 12288];
    const int tid = threadIdx.x;
    const int lane = tid & 63;
    const int wave = tid >> 6;            // 0..7
    const int wm = wave >> 1;             // 0..3: A 64-row block
    const int wn = wave & 1;              // 0..1: B 64-col block

    // XCD chunking (r6/r9 empirical best): 1568 blocks = 8 XCD x (28 by x 7 bx), by FAST.
    int b0 = (int)blockIdx.x;
    int xcd = b0 & 7, w = b0 >> 3;
    int by = w % 28;
    int bx = xcd * 7 + w / 28;
    const int row0 = by * 256, col0 = bx * 128;

    const int lr = lane & 15, lk = lane >> 4;
    const int xk = (lk ^ ((lr >> 1) & 3)) * 8;
    const int aBase = (wm * 64 + lr) * 32 + xk;          // + u*512
    const int bBase = 8192 + (wn * 64 + lr) * 32 + xk;   // + v*512

    // staging: wave w stages A rows w*16..w*16+15 (+128), B rows w*16..w*16+15
    const int srow = wave * 16 + (lane >> 2);
    const int sc = ((lane & 3) ^ ((lane >> 3) & 3)) * 8;   // pre-swizzled source chunk
    const _Float16* pA = Rcat + (size_t)(row0 + srow) * KC + sc;
    const _Float16* pB = Dcat + (size_t)(col0 + srow) * KC + sc;
    const int dA1 = wave * 512, dA2 = 4096 + wave * 512, dB = 8192 + wave * 512;

    auto STAGE = [&](int h) {
        int q = (h % 3) * 12288;
        int off = h * 32;
        gload16(pA + off, &lds[q + dA1]);
        gload16(pA + (size_t)128 * KC + off, &lds[q + dA2]);
        gload16(pB + off, &lds[q + dB]);
    };

    f32x4 acc[4][4];
#pragma unroll
    for (int u = 0; u < 4; u++)
#pragma unroll
        for (int v = 0; v < 4; v++) {
            f32x4 zz = {0.f, 0.f, 0.f, 0.f};
            acc[u][v] = zz;
        }

    // prologue: halves 0,1 in flight; wait for half 0 (3 newest outstanding = half 1)
    STAGE(0);
    STAGE(1);
    asm volatile("s_waitcnt vmcnt(3)" ::: "memory");
    __builtin_amdgcn_s_barrier();

    for (int h = 0; h < NH; ++h) {
        const int q = (h % 3) * 12288;
        int hn = h + 2; if (hn > NH - 1) hn = NH - 1;   // clamped dup stage (same bytes)
        STAGE(hn);
        // 6 newest outstanding = stages issued this iter and last -> half h landed
        asm volatile("s_waitcnt vmcnt(6)" ::: "memory");
        __builtin_amdgcn_s_barrier();

        half8 aF[4], bF[4];
#pragma unroll
        for (int u = 0; u < 4; ++u)
            aF[u] = *(const half8*)&lds[q + aBase + u * 512];
#pragma unroll
        for (int v = 0; v < 4; ++v)
            bF[v] = *(const half8*)&lds[q + bBase + v * 512];

        __builtin_amdgcn_s_setprio(1);
#pragma unroll
        for (int u = 0; u < 4; ++u)
#pragma unroll
            for (int v = 0; v < 4; ++v)
                acc[u][v] = __builtin_amdgcn_mfma_f32_16x16x32_f16(aF[u], bF[v], acc[u][v], 0, 0, 0);
        __builtin_amdgcn_s_setprio(0);

        asm volatile("s_waitcnt lgkmcnt(0)" ::: "memory");   // all reads of buf q retired
        __builtin_amdgcn_s_barrier();
    }
    asm volatile("s_waitcnt vmcnt(0)" ::: "memory");

    // argmax epilogue: C/D layout col=lane&15, row=(lane>>4)*4+j
    unsigned long long* kseg = keys + (size_t)seg * NP;
#pragma unroll
    for (int u = 0; u < 4; u++)
#pragma unroll
        for (int j = 0; j < 4; j++) {
            unsigned long long key = 0ull;
#pragma unroll
            for (int v = 0; v < 4; v++) {
                int gc = col0 + wn * 64 + v * 16 + lr;
                if (gc < NP) {
                    unsigned int bits = __float_as_uint(fabsf(acc[u][v][j]));
                    unsigned long long k2 = ((unsigned long long)bits << 32) |
                                            (unsigned long long)(0xFFFFFFFFu - (unsigned int)gc);
                    key = (k2 > key) ? k2 : key;
                }
            }
#pragma unroll
            for (int m = 1; m < 16; m <<= 1) {
                unsigned long long o = shfl_xor_u64(key, m);
                key = (o > key) ? o : key;
            }
            if (lr == 0) {
                int gr = row0 + wm * 64 + u * 16 + lk * 4 + j;
                if (gr < NP) atomicMax(kseg + gr, key);
            }
        }
}

// ------- wave-parallel least squares + FUSED residual split: one wave per patch -------
template <int M>
__global__ __launch_bounds__(256) void solve_kernel(
    const float* __restrict__ yb, const float* __restrict__ dict,
    const unsigned long long* __restrict__ keys9,
    int* __restrict__ idxb, float* __restrict__ alphab,
    _Float16* __restrict__ Rcat) {
    int n = (blockIdx.x * 256 + threadIdx.x) >> 6;   // grid = NP/4 blocks exact
    int lane = threadIdx.x & 63;
    int g = lane >> 4, t = lane & 15;                // channel group, lane-in-group

    int newidx = 0;
    if (M >= 2) newidx = (int)(0xFFFFFFFFu -
        (unsigned int)(keys9[(size_t)(M - 2) * NP + n] & 0xFFFFFFFFull));
    if (lane == 0) {
        if (M == 1) idxb[n * NA] = n;                // index[:,0] = arange
        else        idxb[n * NA + (M - 1)] = newidx;
    }

    int id[M];
#pragma unroll
    for (int k = 0; k < M; k++)
        id[k] = (k == 0) ? n : ((M >= 2 && k == M - 1) ? newidx : idxb[n * NA + k]);

    const int b = n * CCH + g;
    const int base_c = g * HW;

    constexpr int TRI = M * (M + 1) / 2;
    float G[TRI];
    float rhs[M];
#pragma unroll
    for (int q = 0; q < TRI; q++) G[q] = 0.f;
#pragma unroll
    for (int k = 0; k < M; k++) rhs[k] = 0.f;

    // lanes split the 49 pixels: p = t, t+16, t+32 (+48 on t==0)
#pragma unroll
    for (int rep = 0; rep < 4; rep++) {
        int p = t + rep * 16;
        if (p < HW) {
            float a[M];
#pragma unroll
            for (int k = 0; k < M; k++)
                a[k] = dict[(size_t)id[k] * KF + base_c + p];
            float yp = yb[(size_t)b * HW + p];
#pragma unroll
            for (int k = 0; k < M; k++) {
                rhs[k] = fmaf(a[k], yp, rhs[k]);
#pragma unroll
                for (int l = 0; l <= k; l++)
                    G[k * (k + 1) / 2 + l] = fmaf(a[k], a[l], G[k * (k + 1) / 2 + l]);
            }
        }
    }

    // tree-reduce across the 16-lane group (xor masks 1..8 stay in-group)
#pragma unroll
    for (int m = 1; m < 16; m <<= 1) {
#pragma unroll
        for (int q = 0; q < TRI; q++) G[q] += __shfl_xor(G[q], m, 64);
#pragma unroll
        for (int k = 0; k < M; k++) rhs[k] += __shfl_xor(rhs[k], m, 64);
    }

    // Cholesky in place (redundant on all lanes; store inverse diagonal)
#pragma unroll
    for (int k = 0; k < M; k++) {
        float s = G[k * (k + 1) / 2 + k];
#pragma unroll
        for (int j = 0; j < k; j++) {
            float l = G[k * (k + 1) / 2 + j];
            s = fmaf(-l, l, s);
        }
        float inv = 1.0f / sqrtf(fmaxf(s, 1e-30f));
        G[k * (k + 1) / 2 + k] = inv;
#pragma unroll
        for (int r = k + 1; r < M; r++) {
            float tt = G[r * (r + 1) / 2 + k];
#pragma unroll
            for (int j = 0; j < k; j++)
                tt = fmaf(-G[r * (r + 1) / 2 + j], G[k * (k + 1) / 2 + j], tt);
            G[r * (r + 1) / 2 + k] = tt * inv;
        }
    }
    // forward: L z = rhs
#pragma unroll
    for (int k = 0; k < M; k++) {
        float tt = rhs[k];
#pragma unroll
        for (int j = 0; j < k; j++) tt = fmaf(-G[k * (k + 1) / 2 + j], rhs[j], tt);
        rhs[k] = tt * G[k * (k + 1) / 2 + k];
    }
    // backward: L^T alpha = z
#pragma unroll
    for (int k = M - 1; k >= 0; k--) {
        float tt = rhs[k];
#pragma unroll
        for (int j = k + 1; j < M; j++) tt = fmaf(-G[j * (j + 1) / 2 + k], rhs[j], tt);
        rhs[k] = tt * G[k * (k + 1) / 2 + k];
    }

    if (t == 0) {
#pragma unroll
        for (int k = 0; k < M; k++) alphab[(size_t)b * NA + k] = rhs[k];
    }

    // FUSED residual -> fp16 hi/hi/lo segments (same pixels this lane already owns)
    if (M < NA) {
        _Float16* r0 = Rcat + (size_t)n * KC + base_c;
#pragma unroll
        for (int rep = 0; rep < 4; rep++) {
            int p = t + rep * 16;
            if (p < HW) {
                float s = yb[(size_t)b * HW + p];
#pragma unroll
                for (int k = 0; k < M; k++)
                    s = fmaf(-rhs[k], dict[(size_t)id[k] * KF + base_c + p], s);
                _Float16 hi = (_Float16)s;
                r0[p] = hi;
                r0[KSEG + p] = hi;
                r0[2 * KSEG + p] = (_Float16)(s - (float)hi);
            }
        }
    }
}

// ---------------- stage A: per-patch HR reconstruction (fp16, half8 gathers) ----------
__global__ __launch_bounds__(256) void recon_kernel(
    const float* __restrict__ alphab, const int* __restrict__ idxb,
    const _Float16* __restrict__ hd, _Float16* __restrict__ hr_p) {
    int n = blockIdx.x;
    int tid = threadIdx.x;
    __shared__ float al[CCH * NA];
    __shared__ int idn[NA];
    if (tid < CCH * NA) al[tid] = alphab[(size_t)n * CCH * NA + tid];
    if (tid < NA) idn[tid] = idxb[n * NA + tid];
    __syncthreads();
    for (int v = tid; v < (CCH * HWR) / 8; v += 256) {   // 392 vecs of 8
        int c = v / (HWR / 8);                            // 98 vecs/channel
        float s[8] = {0.f, 0.f, 0.f, 0.f, 0.f, 0.f, 0.f, 0.f};
#pragma unroll
        for (int k = 0; k < NA; k++) {
            half8 d = *(const half8*)&hd[(size_t)idn[k] * (CCH * HWR) + v * 8];
            float ak = al[c * NA + k];
#pragma unroll
            for (int e = 0; e < 8; e++) s[e] = fmaf(ak, (float)d[e], s[e]);
        }
        half8 o;
#pragma unroll
        for (int e = 0; e < 8; e++) o[e] = (_Float16)s[e];
        *(half8*)&hr_p[(size_t)n * (CCH * HWR) + v * 8] = o;
    }
}

// ---------------- stage B: streaming fold + finalize ----------------
__global__ __launch_bounds__(256) void fold2_kernel(
    const _Float16* __restrict__ hr_p, const float* __restrict__ divisor,
    const float* __restrict__ hrms, const float* __restrict__ lms,
    float* __restrict__ out) {
    int gid = blockIdx.x * 256 + threadIdx.x;  // 4*1024*1024 exact
    int x  = gid & 1023;
    int yy = (gid >> 10) & 1023;
    int c  = gid >> 20;

    int t0 = yy - 27;
    int py0 = (t0 > 0) ? (t0 + 11) / 12 : 0;
    int py1 = min(83, yy / 12);
    int s0 = x - 27;
    int px0 = (s0 > 0) ? (s0 + 11) / 12 : 0;
    int px1 = min(83, x / 12);

    float acc = 0.f;
    for (int py = py0; py <= py1; py++) {
        int qy = yy - py * 12;
        for (int px = px0; px <= px1; px++) {
            int qx = x - px * 12;
            int n = py * NPS + px;
            acc += (float)hr_p[(size_t)n * (CCH * HWR) + c * HWR + qy * 28 + qx];
        }
    }
    out[gid] = acc / (divisor[gid] + 1e-8f) + hrms[gid] + lms[gid];
}

// ---------------- fallback one-stage fold (if ws too small for hd16/hr_p) -------------
__global__ __launch_bounds__(256) void fold_final_kernel(
    const float* __restrict__ alphab, const int* __restrict__ idxb,
    const float* __restrict__ hr_dict, const float* __restrict__ divisor,
    const float* __restrict__ hrms, const float* __restrict__ lms,
    float* __restrict__ out) {
    int gid = blockIdx.x * 256 + threadIdx.x;
    int x  = gid & 1023;
    int yy = (gid >> 10) & 1023;
    int c  = gid >> 20;
    int t0 = yy - 27;
    int py0 = (t0 > 0) ? (t0 + 11) / 12 : 0;
    int py1 = min(83, yy / 12);
    int s0 = x - 27;
    int px0 = (s0 > 0) ? (s0 + 11) / 12 : 0;
    int px1 = min(83, x / 12);
    float acc = 0.f;
    for (int py = py0; py <= py1; py++) {
        int qy = yy - py * 12;
        for (int px = px0; px <= px1; px++) {
            int qx = x - px * 12;
            int n = py * NPS + px;
            const float* al = alphab + (size_t)(n * CCH + c) * NA;
            const int* idn = idxb + n * NA;
            int q = qy * 28 + qx;
            float s = 0.f;
#pragma unroll
            for (int k = 0; k < NA; k++)
                s = fmaf(al[k], hr_dict[(size_t)idn[k] * (CCH * HWR) + c * HWR + q], s);
            acc += s;
        }
    }
    out[gid] = acc / (divisor[gid] + 1e-8f) + hrms[gid] + lms[gid];
}

// ---------------- launch ----------------
extern "C" void kernel_launch(void* const* d_in, const int* in_sizes, int n_in,
                              void* d_out, int out_size, void* d_ws, size_t ws_size,
                              hipStream_t stream) {
    const float* hrms    = (const float*)d_in[0];
    const float* ms      = (const float*)d_in[1];
    const float* lms     = (const float*)d_in[2];
    const float* lr_dict = (const float*)d_in[3];
    const float* hr_dict = (const float*)d_in[4];
    const float* divisor = (const float*)d_in[5];
    float* out = (float*)d_out;

    char* ws = (char*)d_ws;
    size_t off = 0;
    auto alloc = [&](size_t bytes) -> void* {
        void* p = ws + off;
        off += (bytes + 255) & ~(size_t)255;
        return p;
    };
    float* htmp   = (float*)alloc((size_t)4 * 1024 * 256 * 4);
    float* diff   = (float*)alloc((size_t)4 * 256 * 256 * 4);
    float* yb     = (float*)alloc((size_t)NP * CCH * HW * 4);
    float* alphab = (float*)alloc((size_t)NP * CCH * NA * 4);
    int*   idxb   = (int*)alloc((size_t)NP * NA * 4);
    unsigned long long* keys9 = (unsigned long long*)alloc((size_t)NP * 9 * 8);
    _Float16* Dcat = (_Float16*)alloc((size_t)NP2 * KC * 2);
    _Float16* Rcat = (_Float16*)alloc((size_t)NP2 * KC * 2);
    _Float16* hd16 = (_Float16*)alloc((size_t)NP * CCH * HWR * 2);
    _Float16* hr_p = (_Float16*)alloc((size_t)NP * CCH * HWR * 2);
    bool two_stage = (off <= ws_size);

    hpass_kernel<<<4096, 256, 0, stream>>>(hrms, htmp);
    vpass_kernel<<<1024, 256, 0, stream>>>(htmp, ms, diff);
    build_y_kernel<<<(NP * CCH * HW + 255) / 256, 256, 0, stream>>>(diff, yb);
    splitcat_kernel<<<(NP2 * 76) / 256, 256, 0, stream>>>(lr_dict, Dcat);
    hipMemsetAsync(keys9, 0, (size_t)NP * 9 * 8, stream);
    if (two_stage)
        hd16_kernel<<<((NP * CCH * HWR) / 8 + 255) / 256, 256, 0, stream>>>(hr_dict, hd16);

    int sblocks = NP / 4;                       // 1764: one wave per patch
    for (int i = 0; i < NA; i++) {
        if (i > 0)
            mfma_argmax_kernel<<<1568, 512, 0, stream>>>(Rcat, Dcat, keys9, i - 1);
        switch (i + 1) {
            case 1:  solve_kernel<1><<<sblocks, 256, 0, stream>>>(yb, lr_dict, keys9, idxb, alphab, Rcat); break;
            case 2:  solve_kernel<2><<<sblocks, 256, 0, stream>>>(yb, lr_dict, keys9, idxb, alphab, Rcat); break;
            case 3:  solve_kernel<3><<<sblocks, 256, 0, stream>>>(yb, lr_dict, keys9, idxb, alphab, Rcat); break;
            case 4:  solve_kernel<4><<<sblocks, 256, 0, stream>>>(yb, lr_dict, keys9, idxb, alphab, Rcat); break;
            case 5:  solve_kernel<5><<<sblocks, 256, 0, stream>>>(yb, lr_dict, keys9, idxb, alphab, Rcat); break;
            case 6:  solve_kernel<6><<<sblocks, 256, 0, stream>>>(yb, lr_dict, keys9, idxb, alphab, Rcat); break;
            case 7:  solve_kernel<7><<<sblocks, 256, 0, stream>>>(yb, lr_dict, keys9, idxb, alphab, Rcat); break;
            case 8:  solve_kernel<8><<<sblocks, 256, 0, stream>>>(yb, lr_dict, keys9, idxb, alphab, Rcat); break;
            case 9:  solve_kernel<9><<<sblocks, 256, 0, stream>>>(yb, lr_dict, keys9, idxb, alphab, Rcat); break;
            case 10: solve_kernel<10><<<sblocks, 256, 0, stream>>>(yb, lr_dict, keys9, idxb, alphab, Rcat); break;
        }
    }

    if (two_stage) {
        recon_kernel<<<NP, 256, 0, stream>>>(alphab, idxb, hd16, hr_p);
        fold2_kernel<<<(4 * 1024 * 1024) / 256, 256, 0, stream>>>(hr_p, divisor, hrms, lms, out);
    } else {
        fold_final_kernel<<<(4 * 1024 * 1024) / 256, 256, 0, stream>>>(
            alphab, idxb, hr_dict, divisor, hrms, lms, out);
    }
}

// Round 15
// 1088.302 us; speedup vs baseline: 6.0230x; 1.0251x over previous
//
#include <hip/hip_runtime.h>
#include <math.h>

#define NP    7056
#define NP2   7168   // padded row count
#define NPS   84
#define CCH   4
#define HW    49
#define HWR   784
#define KF    196    // CCH*HW
#define KSEG  196    // one split segment
#define KC    608    // 3*196 = 588, padded to 19 half-K steps of 32
#define NH    19     // half-K steps of 32
#define NA    10
#define SLR   256
#define GK    17

typedef _Float16 half8 __attribute__((ext_vector_type(8)));
typedef float f32x4 __attribute__((ext_vector_type(4)));

// ---------------- separable gaussian blur (only at subsampled points) ----------------
__global__ void hpass_kernel(const float* __restrict__ hr, float* __restrict__ htmp) {
    __shared__ float g[GK];
    int tid = threadIdx.x;
    if (tid < GK) {
        double s = 0.0, mine = 0.0;
        for (int k = 0; k < GK; k++) {
            double ax = (double)k - 8.0;
            double e = exp(-ax * ax / 32.0);
            s += e;
            if (k == tid) mine = e;
        }
        g[tid] = (float)(mine / s);
    }
    __syncthreads();
    int gid = blockIdx.x * 256 + tid;      // 4*1024*256 exact
    int xs = gid & 255;
    int y  = (gid >> 8) & 1023;
    int c  = gid >> 18;
    const float* row = hr + (size_t)(c * 1024 + y) * 1024;
    int xb = xs * 4 - 6;
    float acc = 0.f;
#pragma unroll
    for (int k = 0; k < GK; k++) {
        int xc = xb + k;
        float v = (xc >= 0 && xc < 1024) ? row[xc] : 0.f;
        acc = fmaf(g[k], v, acc);
    }
    htmp[gid] = acc;
}

__global__ void vpass_kernel(const float* __restrict__ htmp, const float* __restrict__ ms,
                             float* __restrict__ diff) {
    __shared__ float g[GK];
    int tid = threadIdx.x;
    if (tid < GK) {
        double s = 0.0, mine = 0.0;
        for (int k = 0; k < GK; k++) {
            double ax = (double)k - 8.0;
            double e = exp(-ax * ax / 32.0);
            s += e;
            if (k == tid) mine = e;
        }
        g[tid] = (float)(mine / s);
    }
    __syncthreads();
    int gid = blockIdx.x * 256 + tid;      // 4*256*256 exact
    int xs = gid & 255;
    int ys = (gid >> 8) & 255;
    int c  = gid >> 16;
    int yb = ys * 4 - 6;
    float acc = 0.f;
#pragma unroll
    for (int k = 0; k < GK; k++) {
        int yc = yb + k;
        float v = (yc >= 0 && yc < 1024) ? htmp[(size_t)(c * 1024 + yc) * 256 + xs] : 0.f;
        acc = fmaf(g[k], v, acc);
    }
    diff[gid] = ms[gid] - acc;
}

// ---------------- unfold residual patches: y[b=n*4+c][p] ----------------
__global__ void build_y_kernel(const float* __restrict__ diff, float* __restrict__ yb) {
    int gid = blockIdx.x * 256 + threadIdx.x;
    if (gid >= NP * CCH * HW) return;
    int p = gid % HW;
    int b = gid / HW;
    int c = b & 3;
    int n = b >> 2;
    int py = n / NPS, px = n % NPS;
    int dy = p / 7, dx = p % 7;
    yb[gid] = diff[(size_t)(c * SLR + py * 3 + dy) * SLR + px * 3 + dx];
}

// ---------------- dict -> concatenated split [Dh | Dl | Dh | 0pad], K=608, half8 -------
__global__ void splitcat_kernel(const float* __restrict__ src, _Float16* __restrict__ Dcat) {
    int gid = blockIdx.x * 256 + threadIdx.x;   // NP2*76 exact
    int r = gid / 76, v8 = gid - r * 76;
    const float* srow = src + (size_t)r * KF;
    bool valid = (r < NP);
    half8 o;
#pragma unroll
    for (int e = 0; e < 8; e++) {
        int k = v8 * 8 + e;
        int seg = (k >= 392) ? 2 : (k >= 196 ? 1 : 0);
        int ks = k - seg * 196;
        float x = (valid && k < 588) ? srow[ks] : 0.f;
        _Float16 hi = (_Float16)x;
        o[e] = (seg == 1) ? (_Float16)(x - (float)hi) : hi;
    }
    *(half8*)&Dcat[(size_t)r * KC + v8 * 8] = o;
}

// ---------------- fp32 hr_dict -> fp16 (vectorized) ----------------
__global__ void hd16_kernel(const float* __restrict__ hr_dict, _Float16* __restrict__ hd) {
    int gid = blockIdx.x * 256 + threadIdx.x;
    if (gid >= (NP * CCH * HWR) / 8) return;
    const float4 a = *(const float4*)&hr_dict[(size_t)gid * 8];
    const float4 b = *(const float4*)&hr_dict[(size_t)gid * 8 + 4];
    half8 o;
    o[0] = (_Float16)a.x; o[1] = (_Float16)a.y; o[2] = (_Float16)a.z; o[3] = (_Float16)a.w;
    o[4] = (_Float16)b.x; o[5] = (_Float16)b.y; o[6] = (_Float16)b.z; o[7] = (_Float16)b.w;
    *(half8*)&hd[(size_t)gid * 8] = o;
}

// ---- 256x128x608 MFMA GEMM + row argmax, 3-buf pipeline, SINGLE barrier per step ----
__device__ __forceinline__ unsigned long long shfl_xor_u64(unsigned long long v, int m) {
    unsigned int lo = (unsigned int)v;
    unsigned int hi = (unsigned int)(v >> 32);
    lo = __shfl_xor(lo, m, 64);
    hi = __shfl_xor(hi, m, 64);
    return ((unsigned long long)hi << 32) | (unsigned long long)lo;
}

__device__ __forceinline__ void gload16(const void* g, void* l) {
    __builtin_amdgcn_global_load_lds((const __attribute__((address_space(1))) void*)(void*)g,
                                     (__attribute__((address_space(3))) void*)l, 16, 0, 0);
}

// LDS (halves): buf q in {0,1,2} at q*12288: A half [256 rows][32 k] at 0,
// B half [128 rows][32 k] at 8192. Slot XOR applied on pre-swizzled GLOBAL
// source (LDS dest linear) and on reads.
//
// Single-barrier schedule (race-freedom): STAGE(h+2) at step h writes buf
// (h-1)%3, last read in step h-1; every wave's lgkmcnt(0) at END of body h-1
// (reads retired into regs) precedes the barrier at TOP of step h, and STAGE
// issues only after that barrier -> write-after-read is ordered.
// vmcnt invariant: at step h's vmcnt(3), outstanding = {STAGE(h), STAGE(h+1)}
// (<=6); wait-3 => STAGE(h) landed, STAGE(h+1) stays in flight (never 0).
__global__ __launch_bounds__(512, 4) void mfma_argmax_kernel(
    const _Float16* __restrict__ Rcat, const _Float16* __restrict__ Dcat,
    unsigned long long* __restrict__ keys, int seg) {
    __shared__ __align__(16) _Float16 lds[3 * 12288];
    const int tid = threadIdx.x;
    const int lane = tid & 63;
    const int wave = tid >> 6;            // 0..7
    const int wm = wave >> 1;             // 0..3: A 64-row block
    const int wn = wave & 1;              // 0..1: B 64-col block

    // XCD chunking (r6/r9 empirical best): 1568 blocks = 8 XCD x (28 by x 7 bx), by FAST.
    int b0 = (int)blockIdx.x;
    int xcd = b0 & 7, w = b0 >> 3;
    int by = w % 28;
    int bx = xcd * 7 + w / 28;
    const int row0 = by * 256, col0 = bx * 128;

    const int lr = lane & 15, lk = lane >> 4;
    const int xk = (lk ^ ((lr >> 1) & 3)) * 8;
    const int aBase = (wm * 64 + lr) * 32 + xk;          // + u*512
    const int bBase = 8192 + (wn * 64 + lr) * 32 + xk;   // + v*512

    // staging: wave w stages A rows w*16..w*16+15 (+128), B rows w*16..w*16+15
    const int srow = wave * 16 + (lane >> 2);
    const int sc = ((lane & 3) ^ ((lane >> 3) & 3)) * 8;   // pre-swizzled source chunk
    const _Float16* pA = Rcat + (size_t)(row0 + srow) * KC + sc;
    const _Float16* pB = Dcat + (size_t)(col0 + srow) * KC + sc;
    const int dA1 = wave * 512, dA2 = 4096 + wave * 512, dB = 8192 + wave * 512;

    auto STAGE = [&](int h) {
        int q = (h % 3) * 12288;
        int off = h * 32;
        gload16(pA + off, &lds[q + dA1]);
        gload16(pA + (size_t)128 * KC + off, &lds[q + dA2]);
        gload16(pB + off, &lds[q + dB]);
    };

    f32x4 acc[4][4];
#pragma unroll
    for (int u = 0; u < 4; u++)
#pragma unroll
        for (int v = 0; v < 4; v++) {
            f32x4 zz = {0.f, 0.f, 0.f, 0.f};
            acc[u][v] = zz;
        }

    // prologue: halves 0,1 in flight
    STAGE(0);
    STAGE(1);

    for (int h = 0; h < NH; ++h) {
        const int q = (h % 3) * 12288;
        int hn = h + 2; if (hn > NH - 1) hn = NH - 1;   // clamped dup stage (same bytes)

        // single sync point: STAGE(h) landed + all waves' prior-step reads retired
        asm volatile("s_waitcnt vmcnt(3)" ::: "memory");
        __builtin_amdgcn_s_barrier();

        STAGE(hn);                        // writes buf (h-1)%3 — safe post-barrier

        half8 aF[4], bF[4];
#pragma unroll
        for (int u = 0; u < 4; ++u)
            aF[u] = *(const half8*)&lds[q + aBase + u * 512];
#pragma unroll
        for (int v = 0; v < 4; ++v)
            bF[v] = *(const half8*)&lds[q + bBase + v * 512];

        __builtin_amdgcn_s_setprio(1);
#pragma unroll
        for (int u = 0; u < 4; ++u)
#pragma unroll
            for (int v = 0; v < 4; ++v)
                acc[u][v] = __builtin_amdgcn_mfma_f32_16x16x32_f16(aF[u], bF[v], acc[u][v], 0, 0, 0);
        __builtin_amdgcn_s_setprio(0);

        asm volatile("s_waitcnt lgkmcnt(0)" ::: "memory");   // my reads retired pre-barrier
    }
    asm volatile("s_waitcnt vmcnt(0)" ::: "memory");

    // argmax epilogue: C/D layout col=lane&15, row=(lane>>4)*4+j
    unsigned long long* kseg = keys + (size_t)seg * NP;
#pragma unroll
    for (int u = 0; u < 4; u++)
#pragma unroll
        for (int j = 0; j < 4; j++) {
            unsigned long long key = 0ull;
#pragma unroll
            for (int v = 0; v < 4; v++) {
                int gc = col0 + wn * 64 + v * 16 + lr;
                if (gc < NP) {
                    unsigned int bits = __float_as_uint(fabsf(acc[u][v][j]));
                    unsigned long long k2 = ((unsigned long long)bits << 32) |
                                            (unsigned long long)(0xFFFFFFFFu - (unsigned int)gc);
                    key = (k2 > key) ? k2 : key;
                }
            }
#pragma unroll
            for (int m = 1; m < 16; m <<= 1) {
                unsigned long long o = shfl_xor_u64(key, m);
                key = (o > key) ? o : key;
            }
            if (lr == 0) {
                int gr = row0 + wm * 64 + u * 16 + lk * 4 + j;
                if (gr < NP) atomicMax(kseg + gr, key);
            }
        }
}

// ------- wave-parallel least squares + FUSED residual split: one wave per patch -------
template <int M>
__global__ __launch_bounds__(256) void solve_kernel(
    const float* __restrict__ yb, const float* __restrict__ dict,
    const unsigned long long* __restrict__ keys9,
    int* __restrict__ idxb, float* __restrict__ alphab,
    _Float16* __restrict__ Rcat) {
    int n = (blockIdx.x * 256 + threadIdx.x) >> 6;   // grid = NP/4 blocks exact
    int lane = threadIdx.x & 63;
    int g = lane >> 4, t = lane & 15;                // channel group, lane-in-group

    int newidx = 0;
    if (M >= 2) newidx = (int)(0xFFFFFFFFu -
        (unsigned int)(keys9[(size_t)(M - 2) * NP + n] & 0xFFFFFFFFull));
    if (lane == 0) {
        if (M == 1) idxb[n * NA] = n;                // index[:,0] = arange
        else        idxb[n * NA + (M - 1)] = newidx;
    }

    int id[M];
#pragma unroll
    for (int k = 0; k < M; k++)
        id[k] = (k == 0) ? n : ((M >= 2 && k == M - 1) ? newidx : idxb[n * NA + k]);

    const int b = n * CCH + g;
    const int base_c = g * HW;

    constexpr int TRI = M * (M + 1) / 2;
    float G[TRI];
    float rhs[M];
#pragma unroll
    for (int q = 0; q < TRI; q++) G[q] = 0.f;
#pragma unroll
    for (int k = 0; k < M; k++) rhs[k] = 0.f;

    // lanes split the 49 pixels: p = t, t+16, t+32 (+48 on t==0)
#pragma unroll
    for (int rep = 0; rep < 4; rep++) {
        int p = t + rep * 16;
        if (p < HW) {
            float a[M];
#pragma unroll
            for (int k = 0; k < M; k++)
                a[k] = dict[(size_t)id[k] * KF + base_c + p];
            float yp = yb[(size_t)b * HW + p];
#pragma unroll
            for (int k = 0; k < M; k++) {
                rhs[k] = fmaf(a[k], yp, rhs[k]);
#pragma unroll
                for (int l = 0; l <= k; l++)
                    G[k * (k + 1) / 2 + l] = fmaf(a[k], a[l], G[k * (k + 1) / 2 + l]);
            }
        }
    }

    // tree-reduce across the 16-lane group (xor masks 1..8 stay in-group)
#pragma unroll
    for (int m = 1; m < 16; m <<= 1) {
#pragma unroll
        for (int q = 0; q < TRI; q++) G[q] += __shfl_xor(G[q], m, 64);
#pragma unroll
        for (int k = 0; k < M; k++) rhs[k] += __shfl_xor(rhs[k], m, 64);
    }

    // Cholesky in place (redundant on all lanes; store inverse diagonal)
#pragma unroll
    for (int k = 0; k < M; k++) {
        float s = G[k * (k + 1) / 2 + k];
#pragma unroll
        for (int j = 0; j < k; j++) {
            float l = G[k * (k + 1) / 2 + j];
            s = fmaf(-l, l, s);
        }
        float inv = 1.0f / sqrtf(fmaxf(s, 1e-30f));
        G[k * (k + 1) / 2 + k] = inv;
#pragma unroll
        for (int r = k + 1; r < M; r++) {
            float tt = G[r * (r + 1) / 2 + k];
#pragma unroll
            for (int j = 0; j < k; j++)
                tt = fmaf(-G[r * (r + 1) / 2 + j], G[k * (k + 1) / 2 + j], tt);
            G[r * (r + 1) / 2 + k] = tt * inv;
        }
    }
    // forward: L z = rhs
#pragma unroll
    for (int k = 0; k < M; k++) {
        float tt = rhs[k];
#pragma unroll
        for (int j = 0; j < k; j++) tt = fmaf(-G[k * (k + 1) / 2 + j], rhs[j], tt);
        rhs[k] = tt * G[k * (k + 1) / 2 + k];
    }
    // backward: L^T alpha = z
#pragma unroll
    for (int k = M - 1; k >= 0; k--) {
        float tt = rhs[k];
#pragma unroll
        for (int j = k + 1; j < M; j++) tt = fmaf(-G[j * (j + 1) / 2 + k], rhs[j], tt);
        rhs[k] = tt * G[k * (k + 1) / 2 + k];
    }

    if (t == 0) {
#pragma unroll
        for (int k = 0; k < M; k++) alphab[(size_t)b * NA + k] = rhs[k];
    }

    // FUSED residual -> fp16 hi/hi/lo segments (same pixels this lane already owns)
    if (M < NA) {
        _Float16* r0 = Rcat + (size_t)n * KC + base_c;
#pragma unroll
        for (int rep = 0; rep < 4; rep++) {
            int p = t + rep * 16;
            if (p < HW) {
                float s = yb[(size_t)b * HW + p];
#pragma unroll
                for (int k = 0; k < M; k++)
                    s = fmaf(-rhs[k], dict[(size_t)id[k] * KF + base_c + p], s);
                _Float16 hi = (_Float16)s;
                r0[p] = hi;
                r0[KSEG + p] = hi;
                r0[2 * KSEG + p] = (_Float16)(s - (float)hi);
            }
        }
    }
}

// ---------------- stage A: per-patch HR reconstruction (fp16, half8 gathers) ----------
__global__ __launch_bounds__(256) void recon_kernel(
    const float* __restrict__ alphab, const int* __restrict__ idxb,
    const _Float16* __restrict__ hd, _Float16* __restrict__ hr_p) {
    int n = blockIdx.x;
    int tid = threadIdx.x;
    __shared__ float al[CCH * NA];
    __shared__ int idn[NA];
    if (tid < CCH * NA) al[tid] = alphab[(size_t)n * CCH * NA + tid];
    if (tid < NA) idn[tid] = idxb[n * NA + tid];
    __syncthreads();
    for (int v = tid; v < (CCH * HWR) / 8; v += 256) {   // 392 vecs of 8
        int c = v / (HWR / 8);                            // 98 vecs/channel
        float s[8] = {0.f, 0.f, 0.f, 0.f, 0.f, 0.f, 0.f, 0.f};
#pragma unroll
        for (int k = 0; k < NA; k++) {
            half8 d = *(const half8*)&hd[(size_t)idn[k] * (CCH * HWR) + v * 8];
            float ak = al[c * NA + k];
#pragma unroll
            for (int e = 0; e < 8; e++) s[e] = fmaf(ak, (float)d[e], s[e]);
        }
        half8 o;
#pragma unroll
        for (int e = 0; e < 8; e++) o[e] = (_Float16)s[e];
        *(half8*)&hr_p[(size_t)n * (CCH * HWR) + v * 8] = o;
    }
}

// ---------------- stage B: streaming fold + finalize ----------------
__global__ __launch_bounds__(256) void fold2_kernel(
    const _Float16* __restrict__ hr_p, const float* __restrict__ divisor,
    const float* __restrict__ hrms, const float* __restrict__ lms,
    float* __restrict__ out) {
    int gid = blockIdx.x * 256 + threadIdx.x;  // 4*1024*1024 exact
    int x  = gid & 1023;
    int yy = (gid >> 10) & 1023;
    int c  = gid >> 20;

    int t0 = yy - 27;
    int py0 = (t0 > 0) ? (t0 + 11) / 12 : 0;
    int py1 = min(83, yy / 12);
    int s0 = x - 27;
    int px0 = (s0 > 0) ? (s0 + 11) / 12 : 0;
    int px1 = min(83, x / 12);

    float acc = 0.f;
    for (int py = py0; py <= py1; py++) {
        int qy = yy - py * 12;
        for (int px = px0; px <= px1; px++) {
            int qx = x - px * 12;
            int n = py * NPS + px;
            acc += (float)hr_p[(size_t)n * (CCH * HWR) + c * HWR + qy * 28 + qx];
        }
    }
    out[gid] = acc / (divisor[gid] + 1e-8f) + hrms[gid] + lms[gid];
}

// ---------------- fallback one-stage fold (if ws too small for hd16/hr_p) -------------
__global__ __launch_bounds__(256) void fold_final_kernel(
    const float* __restrict__ alphab, const int* __restrict__ idxb,
    const float* __restrict__ hr_dict, const float* __restrict__ divisor,
    const float* __restrict__ hrms, const float* __restrict__ lms,
    float* __restrict__ out) {
    int gid = blockIdx.x * 256 + threadIdx.x;
    int x  = gid & 1023;
    int yy = (gid >> 10) & 1023;
    int c  = gid >> 20;
    int t0 = yy - 27;
    int py0 = (t0 > 0) ? (t0 + 11) / 12 : 0;
    int py1 = min(83, yy / 12);
    int s0 = x - 27;
    int px0 = (s0 > 0) ? (s0 + 11) / 12 : 0;
    int px1 = min(83, x / 12);
    float acc = 0.f;
    for (int py = py0; py <= py1; py++) {
        int qy = yy - py * 12;
        for (int px = px0; px <= px1; px++) {
            int qx = x - px * 12;
            int n = py * NPS + px;
            const float* al = alphab + (size_t)(n * CCH + c) * NA;
            const int* idn = idxb + n * NA;
            int q = qy * 28 + qx;
            float s = 0.f;
#pragma unroll
            for (int k = 0; k < NA; k++)
                s = fmaf(al[k], hr_dict[(size_t)idn[k] * (CCH * HWR) + c * HWR + q], s);
            acc += s;
        }
    }
    out[gid] = acc / (divisor[gid] + 1e-8f) + hrms[gid] + lms[gid];
}

// ---------------- launch ----------------
extern "C" void kernel_launch(void* const* d_in, const int* in_sizes, int n_in,
                              void* d_out, int out_size, void* d_ws, size_t ws_size,
                              hipStream_t stream) {
    const float* hrms    = (const float*)d_in[0];
    const float* ms      = (const float*)d_in[1];
    const float* lms     = (const float*)d_in[2];
    const float* lr_dict = (const float*)d_in[3];
    const float* hr_dict = (const float*)d_in[4];
    const float* divisor = (const float*)d_in[5];
    float* out = (float*)d_out;

    char* ws = (char*)d_ws;
    size_t off = 0;
    auto alloc = [&](size_t bytes) -> void* {
        void* p = ws + off;
        off += (bytes + 255) & ~(size_t)255;
        return p;
    };
    float* htmp   = (float*)alloc((size_t)4 * 1024 * 256 * 4);
    float* diff   = (float*)alloc((size_t)4 * 256 * 256 * 4);
    float* yb     = (float*)alloc((size_t)NP * CCH * HW * 4);
    float* alphab = (float*)alloc((size_t)NP * CCH * NA * 4);
    int*   idxb   = (int*)alloc((size_t)NP * NA * 4);
    unsigned long long* keys9 = (unsigned long long*)alloc((size_t)NP * 9 * 8);
    _Float16* Dcat = (_Float16*)alloc((size_t)NP2 * KC * 2);
    _Float16* Rcat = (_Float16*)alloc((size_t)NP2 * KC * 2);
    _Float16* hd16 = (_Float16*)alloc((size_t)NP * CCH * HWR * 2);
    _Float16* hr_p = (_Float16*)alloc((size_t)NP * CCH * HWR * 2);
    bool two_stage = (off <= ws_size);

    hpass_kernel<<<4096, 256, 0, stream>>>(hrms, htmp);
    vpass_kernel<<<1024, 256, 0, stream>>>(htmp, ms, diff);
    build_y_kernel<<<(NP * CCH * HW + 255) / 256, 256, 0, stream>>>(diff, yb);
    splitcat_kernel<<<(NP2 * 76) / 256, 256, 0, stream>>>(lr_dict, Dcat);
    hipMemsetAsync(keys9, 0, (size_t)NP * 9 * 8, stream);
    if (two_stage)
        hd16_kernel<<<((NP * CCH * HWR) / 8 + 255) / 256, 256, 0, stream>>>(hr_dict, hd16);

    int sblocks = NP / 4;                       // 1764: one wave per patch
    for (int i = 0; i < NA; i++) {
        if (i > 0)
            mfma_argmax_kernel<<<1568, 512, 0, stream>>>(Rcat, Dcat, keys9, i - 1);
        switch (i + 1) {
            case 1:  solve_kernel<1><<<sblocks, 256, 0, stream>>>(yb, lr_dict, keys9, idxb, alphab, Rcat); break;
            case 2:  solve_kernel<2><<<sblocks, 256, 0, stream>>>(yb, lr_dict, keys9, idxb, alphab, Rcat); break;
            case 3:  solve_kernel<3><<<sblocks, 256, 0, stream>>>(yb, lr_dict, keys9, idxb, alphab, Rcat); break;
            case 4:  solve_kernel<4><<<sblocks, 256, 0, stream>>>(yb, lr_dict, keys9, idxb, alphab, Rcat); break;
            case 5:  solve_kernel<5><<<sblocks, 256, 0, stream>>>(yb, lr_dict, keys9, idxb, alphab, Rcat); break;
            case 6:  solve_kernel<6><<<sblocks, 256, 0, stream>>>(yb, lr_dict, keys9, idxb, alphab, Rcat); break;
            case 7:  solve_kernel<7><<<sblocks, 256, 0, stream>>>(yb, lr_dict, keys9, idxb, alphab, Rcat); break;
            case 8:  solve_kernel<8><<<sblocks, 256, 0, stream>>>(yb, lr_dict, keys9, idxb, alphab, Rcat); break;
            case 9:  solve_kernel<9><<<sblocks, 256, 0, stream>>>(yb, lr_dict, keys9, idxb, alphab, Rcat); break;
            case 10: solve_kernel<10><<<sblocks, 256, 0, stream>>>(yb, lr_dict, keys9, idxb, alphab, Rcat); break;
        }
    }

    if (two_stage) {
        recon_kernel<<<NP, 256, 0, stream>>>(alphab, idxb, hd16, hr_p);
        fold2_kernel<<<(4 * 1024 * 1024) / 256, 256, 0, stream>>>(hr_p, divisor, hrms, lms, out);
    } else {
        fold_final_kernel<<<(4 * 1024 * 1024) / 256, 256, 0, stream>>>(
            alphab, idxb, hr_dict, divisor, hrms, lms, out);
    }
}